// Round 4
// baseline (282.833 us; speedup 1.0000x reference)
//
#include <hip/hip_runtime.h>
#include <cstdint>
#include <cstddef>

typedef unsigned short u16;
typedef __attribute__((ext_vector_type(8))) short bf16x8;
typedef __attribute__((ext_vector_type(4))) float f32x4;

#define B_ 4
#define T_ 1024
#define D_ 2048
#define N_ 16
#define H_ 128
#define BT_ (B_ * T_)
#define KMASK (-2.3819763e38f)

__device__ __forceinline__ u16 f2bf(float f) {
  uint32_t u = __builtin_bit_cast(uint32_t, f);
  u += 0x7FFFu + ((u >> 16) & 1u);
  return (u16)(u >> 16);
}

// async global->LDS, 16B per lane; LDS dest linear by lane within the wave.
__device__ __forceinline__ void gload16(const void* g, void* l) {
  __builtin_amdgcn_global_load_lds((const __attribute__((address_space(1))) void*)g,
                                   (__attribute__((address_space(3))) void*)l, 16, 0, 0);
}

// ---------------- convert x (f32 -> bf16), 8 elems/thread ----------------
__global__ __launch_bounds__(256) void convert_x_kernel(const float* __restrict__ x,
                                                        u16* __restrict__ xb) {
  int i = (blockIdx.x * 256 + threadIdx.x) * 8;
  float4 v0 = *(const float4*)(x + i);
  float4 v1 = *(const float4*)(x + i + 4);
  uint4 o;
  o.x = (uint32_t)f2bf(v0.x) | ((uint32_t)f2bf(v0.y) << 16);
  o.y = (uint32_t)f2bf(v0.z) | ((uint32_t)f2bf(v0.w) << 16);
  o.z = (uint32_t)f2bf(v1.x) | ((uint32_t)f2bf(v1.y) << 16);
  o.w = (uint32_t)f2bf(v1.z) | ((uint32_t)f2bf(v1.w) << 16);
  *(uint4*)(xb + i) = o;
}

// ---------- tiled transpose + convert: src f32 [z][R][C] -> dst bf16 [z][C][R] ----------
__global__ __launch_bounds__(256) void transpose_kernel(const float* __restrict__ src,
                                                        u16* __restrict__ dst, int R, int C) {
  __shared__ float tile[32][33];
  const int z = blockIdx.z;
  const float* s = src + (size_t)z * R * C;
  u16* d = dst + (size_t)z * R * C;
  const int tx = threadIdx.x, ty = threadIdx.y;  // 32 x 8
  const int r0 = blockIdx.y * 32, c0 = blockIdx.x * 32;
#pragma unroll
  for (int i = 0; i < 4; ++i)
    tile[ty + i * 8][tx] = s[(size_t)(r0 + ty + i * 8) * C + (c0 + tx)];
  __syncthreads();
#pragma unroll
  for (int i = 0; i < 4; ++i)
    d[(size_t)(c0 + ty + i * 8) * R + (r0 + tx)] = f2bf(tile[tx][ty + i * 8]);
}

// ---------------- RoPE tables: [1024 positions][64] cos/sin ----------------
__global__ __launch_bounds__(256) void rope_table_kernel(float* __restrict__ costab,
                                                         float* __restrict__ sintab) {
  int idx = blockIdx.x * 256 + threadIdx.x;  // 65536
  int p = idx >> 6, i = idx & 63;
  float ts = powf(10000.0f, (float)i * (1.0f / 64.0f));
  float ang = (float)p / ts;
  costab[idx] = cosf(ang);
  sintab[idx] = sinf(ang);
}

// ---------------- fused q/k/v projection GEMM (+RoPE epilogue) ----------------
// grid: (BT/256, 18). 8 waves, wave tile 32x128 (RoPE needs (h,h+64) in-thread).
// BK=64, TRIPLE-buffered LDS, counted vmcnt(6), raw barriers (m201 mechanism).
__global__ __launch_bounds__(512) void proj_gemm_kernel(
    const u16* __restrict__ xb, const u16* __restrict__ wqT, const u16* __restrict__ wkvT,
    const int* __restrict__ segment_pos, const float* __restrict__ costab,
    const float* __restrict__ sintab, u16* __restrict__ qb, u16* __restrict__ kb,
    u16* __restrict__ vT) {
  __shared__ alignas(16) u16 a_lds[3][256 * 64];  // 96 KB
  __shared__ alignas(16) u16 b_lds[3][128 * 64];  // 48 KB
  const int m0 = blockIdx.x * 256;
  const int y = blockIdx.y;
  const u16* Bt = (y < N_) ? (wqT + (size_t)y * H_ * D_) : (wkvT + (size_t)(y - N_) * H_ * D_);
  const int tid = threadIdx.x;
  const int w = tid >> 6, lane = tid & 63;
  const int g = lane >> 4, li = lane & 15;
  f32x4 acc[2][8];
#pragma unroll
  for (int i = 0; i < 2; ++i)
#pragma unroll
    for (int j = 0; j < 8; ++j) acc[i][j] = (f32x4){0.f, 0.f, 0.f, 0.f};

  auto stageA = [&](int buf, int k0) {  // 256x64 tile: 4 loads/thread
#pragma unroll
    for (int it = 0; it < 4; ++it) {
      int chunk = it * 512 + tid;  // 0..2047 16B-units, lane-contiguous per wave
      int row = chunk >> 3, cu = chunk & 7;
      gload16(xb + (size_t)(m0 + row) * D_ + k0 + ((cu ^ (row & 7)) << 3),
              &a_lds[buf][chunk * 8]);
    }
  };
  auto stageB = [&](int buf, int k0) {  // 128x64 tile: 2 loads/thread
#pragma unroll
    for (int it = 0; it < 2; ++it) {
      int chunk = it * 512 + tid;  // 0..1023
      int row = chunk >> 3, cu = chunk & 7;
      gload16(Bt + (size_t)row * D_ + k0 + ((cu ^ (row & 7)) << 3), &b_lds[buf][chunk * 8]);
    }
  };

  const int NT = D_ / 64;  // 32
  stageA(0, 0); stageB(0, 0); stageA(1, 64); stageB(1, 64);  // 12 loads in flight
  asm volatile("s_waitcnt vmcnt(6)" ::: "memory");           // tile 0 landed
  __builtin_amdgcn_sched_barrier(0);
  __builtin_amdgcn_s_barrier();

  for (int t = 0; t < NT; ++t) {
    const int cur = t % 3, nxt = (t + 2) % 3;
    const bool pre = (t + 2 < NT);
    const int kp = (t + 2) * 64;
#pragma unroll
    for (int p = 0; p < 2; ++p) {
      if (p == 0) { if (pre) stageA(nxt, kp); }
      else        { if (pre) stageB(nxt, kp); }
      bf16x8 af[2], bfr[8];
#pragma unroll
      for (int i = 0; i < 2; ++i) {
        int row = w * 32 + i * 16 + li;
        af[i] = *(const bf16x8*)((const char*)&a_lds[cur][0] +
                                 row * 128 + ((p * 64 + g * 16) ^ ((row & 7) << 4)));
      }
#pragma unroll
      for (int j = 0; j < 8; ++j) {
        int row = j * 16 + li;
        bfr[j] = *(const bf16x8*)((const char*)&b_lds[cur][0] +
                                  row * 128 + ((p * 64 + g * 16) ^ ((row & 7) << 4)));
      }
      __builtin_amdgcn_s_barrier();
      asm volatile("s_waitcnt lgkmcnt(0)" ::: "memory");
      __builtin_amdgcn_sched_barrier(0);
      __builtin_amdgcn_s_setprio(1);
#pragma unroll
      for (int i = 0; i < 2; ++i)
#pragma unroll
        for (int j = 0; j < 8; ++j)
          acc[i][j] = __builtin_amdgcn_mfma_f32_16x16x32_bf16(af[i], bfr[j], acc[i][j], 0, 0, 0);
      __builtin_amdgcn_s_setprio(0);
      if (p == 1) {  // once per K-tile: counted wait, never 0 in steady state
        if (pre) asm volatile("s_waitcnt vmcnt(6)" ::: "memory");
        else     asm volatile("s_waitcnt vmcnt(0)" ::: "memory");
        __builtin_amdgcn_sched_barrier(0);
      }
      __builtin_amdgcn_s_barrier();  // publishes all waves' tile-(t+1) loads
    }
  }

  const float scale = 0.08838834764831845f;  // 128^-0.5
  const int b = m0 >> 10;
#pragma unroll
  for (int i = 0; i < 2; ++i) {
    if (y <= N_) {  // q or k : RoPE
#pragma unroll
      for (int r = 0; r < 4; ++r) {
        int bt = m0 + w * 32 + i * 16 + g * 4 + r;
        int t = bt & 1023;
        int p = segment_pos[bt];
        p = p < 0 ? 0 : (p > 1023 ? 1023 : p);
#pragma unroll
        for (int fn = 0; fn < 4; ++fn) {
          int hi = fn * 16 + li;
          float cv = costab[p * 64 + hi], sv = sintab[p * 64 + hi];
          float first = acc[i][fn][r], second = acc[i][fn + 4][r];
          float o1 = first * cv - second * sv;
          float o2 = second * cv + first * sv;
          if (y < N_) {
            u16* dst = qb + ((size_t)(b * N_ + y) * T_ + t) * H_;
            dst[hi] = f2bf(o1 * scale);
            dst[hi + 64] = f2bf(o2 * scale);
          } else {
            u16* dst = kb + (size_t)bt * H_;
            dst[hi] = f2bf(o1);
            dst[hi + 64] = f2bf(o2);
          }
        }
      }
    } else {  // v -> vT[b][h][t], packed along t
      int tbase = (m0 & 1023) + w * 32 + i * 16 + g * 4;
#pragma unroll
      for (int fn = 0; fn < 8; ++fn) {
        int h = fn * 16 + li;
        ushort4 pk;
        pk.x = f2bf(acc[i][fn][0]);
        pk.y = f2bf(acc[i][fn][1]);
        pk.z = f2bf(acc[i][fn][2]);
        pk.w = f2bf(acc[i][fn][3]);
        *(ushort4*)(vT + ((size_t)(b * H_ + h)) * T_ + tbase) = pk;
      }
    }
  }
}

// ---------------- flash attention (swapped-QK, swizzled LDS, 2-phase dbuf) ---------
// grid: (T/64, B*N). qt = 15 - bx (heavy blocks first). 4 waves; wave w owns q rows
// [qt*64+16w, +16). K [64][128] swz, V^T [128][64] swz, P^T per-wave [16][64] swz.
__global__ __launch_bounds__(256) void attn_kernel(const u16* __restrict__ qb,
                                                   const u16* __restrict__ kb,
                                                   const u16* __restrict__ vT,
                                                   u16* __restrict__ enc) {
  __shared__ alignas(16) u16 k_lds[2][64 * 128];
  __shared__ alignas(16) u16 v_lds[2][128 * 64];
  __shared__ alignas(16) u16 p_lds[4 * 16 * 64];
  const int qt = (int)(gridDim.x - 1 - blockIdx.x);
  const int bn = blockIdx.y;
  const int b = bn >> 4, n = bn & 15;
  const int tid = threadIdx.x, w = tid >> 6, lane = tid & 63;
  const int g = lane >> 4, li = lane & 15;
  const int t0 = qt * 64 + w * 16;
  char* pbase = (char*)p_lds + w * 2048;

  bf16x8 qf[4];  // Q as B-fragment: lane -> Q[t0+li][c*32+g*8+e]
  {
    const u16* qrow = qb + ((size_t)(b * N_ + n) * T_ + (t0 + li)) * H_;
#pragma unroll
    for (int c = 0; c < 4; ++c) qf[c] = *(const bf16x8*)(qrow + c * 32 + g * 8);
  }
  f32x4 o[8];
#pragma unroll
  for (int j = 0; j < 8; ++j) o[j] = (f32x4){0.f, 0.f, 0.f, 0.f};
  float m = -3e38f, lsum = 0.f;

  auto stageKV = [&](int buf, int s0) {
#pragma unroll
    for (int it = 0; it < 4; ++it) {
      int chunk = it * 256 + tid;
      int row = chunk >> 4, cu = chunk & 15;
      gload16(kb + ((size_t)b * T_ + s0 + row) * H_ + ((cu ^ (row & 7)) << 3),
              &k_lds[buf][chunk * 8]);
    }
#pragma unroll
    for (int it = 0; it < 4; ++it) {
      int chunk = it * 256 + tid;
      int row = chunk >> 3, cu = chunk & 7;
      gload16(vT + ((size_t)(b * H_ + row)) * T_ + s0 + ((cu ^ (row & 7)) << 3),
              &v_lds[buf][chunk * 8]);
    }
  };

  stageKV(0, 0);
  __syncthreads();
  int cur = 0;
  for (int st = 0; st <= qt; ++st) {
    if (st < qt) stageKV(cur ^ 1, (st + 1) * 64);  // prefetch next K/V tile

    // S^T = K x Q : sacc[fn] lane -> S[t=t0+li][s = s0+fn*16+g*4+r]
    f32x4 sacc[4];
#pragma unroll
    for (int fn = 0; fn < 4; ++fn) sacc[fn] = (f32x4){0.f, 0.f, 0.f, 0.f};
#pragma unroll
    for (int c = 0; c < 4; ++c)
#pragma unroll
      for (int fn = 0; fn < 4; ++fn) {
        int row = fn * 16 + li;
        bf16x8 kf = *(const bf16x8*)((const char*)&k_lds[cur][0] +
                                     row * 256 + ((c * 64 + g * 16) ^ ((row & 7) << 4)));
        sacc[fn] = __builtin_amdgcn_mfma_f32_16x16x32_bf16(kf, qf[c], sacc[fn], 0, 0, 0);
      }

    if (st == qt) {  // diagonal: mask s_local > t_local
#pragma unroll
      for (int fn = 0; fn < 4; ++fn)
#pragma unroll
        for (int r = 0; r < 4; ++r)
          if (fn * 16 + g * 4 + r > w * 16 + li) sacc[fn][r] = KMASK;
    }

    // online softmax: row t = t0+li spread over lanes {li, li+16, li+32, li+48}
    float mx = -3e38f;
#pragma unroll
    for (int fn = 0; fn < 4; ++fn)
#pragma unroll
      for (int r = 0; r < 4; ++r) mx = fmaxf(mx, sacc[fn][r]);
    mx = fmaxf(mx, __shfl_xor(mx, 16, 64));
    mx = fmaxf(mx, __shfl_xor(mx, 32, 64));
    float mn = fmaxf(m, mx);
    float alpha = __expf(m - mn);
    m = mn;
    float ps = 0.f;
#pragma unroll
    for (int fn = 0; fn < 4; ++fn)
#pragma unroll
      for (int r = 0; r < 4; ++r) {
        float p = __expf(sacc[fn][r] - mn);
        sacc[fn][r] = p;
        ps += p;
      }
    ps += __shfl_xor(ps, 16, 64);
    ps += __shfl_xor(ps, 32, 64);
    lsum = lsum * alpha + ps;

    // write P^T rows t=li: 4 x ds_write_b64, s-contiguous (per-wave region, no barrier)
#pragma unroll
    for (int fn = 0; fn < 4; ++fn) {
      ushort4 pk;
      pk.x = f2bf(sacc[fn][0]);
      pk.y = f2bf(sacc[fn][1]);
      pk.z = f2bf(sacc[fn][2]);
      pk.w = f2bf(sacc[fn][3]);
      *(ushort4*)(pbase + li * 128 + ((fn * 32 + g * 8) ^ ((li & 7) << 4))) = pk;
    }

    // rescale O (rows g*4+r) by alpha of that row
#pragma unroll
    for (int r = 0; r < 4; ++r) {
      float ar = __shfl(alpha, g * 4 + r, 64);
#pragma unroll
      for (int hn = 0; hn < 8; ++hn) o[hn][r] *= ar;
    }

    // PV: o[hn] += P(A) x V(B)
#pragma unroll
    for (int c2 = 0; c2 < 2; ++c2) {
      bf16x8 pf = *(const bf16x8*)(pbase + li * 128 + ((c2 * 64 + g * 16) ^ ((li & 7) << 4)));
#pragma unroll
      for (int hn = 0; hn < 8; ++hn) {
        int hrow = hn * 16 + li;
        bf16x8 vf = *(const bf16x8*)((const char*)&v_lds[cur][0] +
                                     hrow * 128 + ((c2 * 64 + g * 16) ^ ((li & 7) << 4)));
        o[hn] = __builtin_amdgcn_mfma_f32_16x16x32_bf16(pf, vf, o[hn], 0, 0, 0);
      }
    }
    __syncthreads();  // drains prefetch; all waves done with buf[cur]
    cur ^= 1;
  }

#pragma unroll
  for (int r = 0; r < 4; ++r) {
    float lr = __shfl(lsum, g * 4 + r, 64);
    float inv = 1.0f / lr;
    int t = qt * 64 + w * 16 + g * 4 + r;
    u16* dst = enc + ((size_t)(b * T_ + t)) * (N_ * H_) + n * H_;
#pragma unroll
    for (int hn = 0; hn < 8; ++hn) dst[hn * 16 + li] = f2bf(o[hn][r] * inv);
  }
}

// ---------------- output projection GEMM: out = enc @ wo_flat ----------------
// grid: (BT/256, D/128) = 256 blocks. 8 waves, wave tile 64x64. Triple-buffered,
// counted vmcnt(6), raw barriers.
__global__ __launch_bounds__(512) void out_gemm_kernel(const u16* __restrict__ enc,
                                                       const u16* __restrict__ woT,
                                                       float* __restrict__ out) {
  __shared__ alignas(16) u16 a_lds[3][256 * 64];
  __shared__ alignas(16) u16 b_lds[3][128 * 64];
  const int m0 = blockIdx.x * 256;
  const int n0 = blockIdx.y * 128;
  const int tid = threadIdx.x, w = tid >> 6, lane = tid & 63;
  const int g = lane >> 4, li = lane & 15;
  const int mrow = (w >> 1) * 64, ncol = (w & 1) * 64;
  f32x4 acc[4][4];
#pragma unroll
  for (int i = 0; i < 4; ++i)
#pragma unroll
    for (int j = 0; j < 4; ++j) acc[i][j] = (f32x4){0.f, 0.f, 0.f, 0.f};

  auto stageA = [&](int buf, int k0) {
#pragma unroll
    for (int it = 0; it < 4; ++it) {
      int chunk = it * 512 + tid;
      int row = chunk >> 3, cu = chunk & 7;
      gload16(enc + (size_t)(m0 + row) * D_ + k0 + ((cu ^ (row & 7)) << 3),
              &a_lds[buf][chunk * 8]);
    }
  };
  auto stageB = [&](int buf, int k0) {
#pragma unroll
    for (int it = 0; it < 2; ++it) {
      int chunk = it * 512 + tid;
      int row = chunk >> 3, cu = chunk & 7;
      gload16(woT + (size_t)(n0 + row) * D_ + k0 + ((cu ^ (row & 7)) << 3),
              &b_lds[buf][chunk * 8]);
    }
  };

  const int NT = D_ / 64;
  stageA(0, 0); stageB(0, 0); stageA(1, 64); stageB(1, 64);
  asm volatile("s_waitcnt vmcnt(6)" ::: "memory");
  __builtin_amdgcn_sched_barrier(0);
  __builtin_amdgcn_s_barrier();

  for (int t = 0; t < NT; ++t) {
    const int cur = t % 3, nxt = (t + 2) % 3;
    const bool pre = (t + 2 < NT);
    const int kp = (t + 2) * 64;
#pragma unroll
    for (int p = 0; p < 2; ++p) {
      if (p == 0) { if (pre) stageA(nxt, kp); }
      else        { if (pre) stageB(nxt, kp); }
      bf16x8 af[4], bfr[4];
#pragma unroll
      for (int i = 0; i < 4; ++i) {
        int row = mrow + i * 16 + li;
        af[i] = *(const bf16x8*)((const char*)&a_lds[cur][0] +
                                 row * 128 + ((p * 64 + g * 16) ^ ((row & 7) << 4)));
      }
#pragma unroll
      for (int j = 0; j < 4; ++j) {
        int row = ncol + j * 16 + li;
        bfr[j] = *(const bf16x8*)((const char*)&b_lds[cur][0] +
                                  row * 128 + ((p * 64 + g * 16) ^ ((row & 7) << 4)));
      }
      __builtin_amdgcn_s_barrier();
      asm volatile("s_waitcnt lgkmcnt(0)" ::: "memory");
      __builtin_amdgcn_sched_barrier(0);
      __builtin_amdgcn_s_setprio(1);
#pragma unroll
      for (int i = 0; i < 4; ++i)
#pragma unroll
        for (int j = 0; j < 4; ++j)
          acc[i][j] = __builtin_amdgcn_mfma_f32_16x16x32_bf16(af[i], bfr[j], acc[i][j], 0, 0, 0);
      __builtin_amdgcn_s_setprio(0);
      if (p == 1) {
        if (pre) asm volatile("s_waitcnt vmcnt(6)" ::: "memory");
        else     asm volatile("s_waitcnt vmcnt(0)" ::: "memory");
        __builtin_amdgcn_sched_barrier(0);
      }
      __builtin_amdgcn_s_barrier();
    }
  }
#pragma unroll
  for (int i = 0; i < 4; ++i)
#pragma unroll
    for (int r = 0; r < 4; ++r) {
      int bt = m0 + mrow + i * 16 + g * 4 + r;
      float* dst = out + (size_t)bt * D_ + n0 + ncol;
#pragma unroll
      for (int j = 0; j < 4; ++j) dst[j * 16 + li] = acc[i][j][r];
    }
}

// ---------------- launch ----------------
extern "C" void kernel_launch(void* const* d_in, const int* in_sizes, int n_in,
                              void* d_out, int out_size, void* d_ws, size_t ws_size,
                              hipStream_t stream) {
  const float* x = (const float*)d_in[0];
  const float* wq = (const float*)d_in[1];
  const float* wkv = (const float*)d_in[2];
  const float* wo = (const float*)d_in[3];
  const int* segment_pos = (const int*)d_in[4];
  // d_in[5] = attn_mask: causal tril for this problem; applied via index causality.
  float* out = (float*)d_out;

  char* ws = (char*)d_ws;
  size_t off = 0;
  auto alloc = [&](size_t bytes) -> void* {
    void* p = ws + off;
    off += (bytes + 255) & ~(size_t)255;
    return p;
  };
  u16* xb   = (u16*)alloc((size_t)BT_ * D_ * 2);
  u16* wqT  = (u16*)alloc((size_t)N_ * H_ * D_ * 2);
  u16* wkvT = (u16*)alloc((size_t)2 * H_ * D_ * 2);
  u16* woT  = (u16*)alloc((size_t)D_ * N_ * H_ * 2);
  u16* qb   = (u16*)alloc((size_t)B_ * N_ * T_ * H_ * 2);
  u16* kb   = (u16*)alloc((size_t)B_ * T_ * H_ * 2);
  u16* vT   = (u16*)alloc((size_t)B_ * H_ * T_ * 2);
  u16* enc  = (u16*)alloc((size_t)BT_ * N_ * H_ * 2);
  float* costab = (float*)alloc(1024 * 64 * 4);
  float* sintab = (float*)alloc(1024 * 64 * 4);

  convert_x_kernel<<<BT_ * D_ / 8 / 256, 256, 0, stream>>>(x, xb);
  dim3 tb(32, 8);
  transpose_kernel<<<dim3(H_ / 32, D_ / 32, N_), tb, 0, stream>>>(wq, wqT, D_, H_);
  transpose_kernel<<<dim3(H_ / 32, D_ / 32, 2), tb, 0, stream>>>(wkv, wkvT, D_, H_);
  transpose_kernel<<<dim3(D_ / 32, D_ / 32, 1), tb, 0, stream>>>(wo, woT, N_ * H_, D_);
  rope_table_kernel<<<256, 256, 0, stream>>>(costab, sintab);
  proj_gemm_kernel<<<dim3(BT_ / 256, N_ + 2), 512, 0, stream>>>(xb, wqT, wkvT, segment_pos,
                                                                costab, sintab, qb, kb, vT);
  attn_kernel<<<dim3(T_ / 64, B_ * N_), 256, 0, stream>>>(qb, kb, vT, enc);
  out_gemm_kernel<<<dim3(BT_ / 256, D_ / 128), 512, 0, stream>>>(enc, woT, out);
}

// Round 5
// 203.123 us; speedup vs baseline: 1.3924x; 1.3924x over previous
//
#include <hip/hip_runtime.h>
#include <cstdint>
#include <cstddef>

typedef unsigned short u16;
typedef __attribute__((ext_vector_type(8))) short bf16x8;
typedef __attribute__((ext_vector_type(4))) float f32x4;

#define B_ 4
#define T_ 1024
#define D_ 2048
#define N_ 16
#define H_ 128
#define BT_ (B_ * T_)
#define KMASK (-2.3819763e38f)

__device__ __forceinline__ u16 f2bf(float f) {
  uint32_t u = __builtin_bit_cast(uint32_t, f);
  u += 0x7FFFu + ((u >> 16) & 1u);
  return (u16)(u >> 16);
}
__device__ __forceinline__ float bf2f(uint32_t u) {
  return __builtin_bit_cast(float, u << 16);
}

// async global->LDS, 16B per lane; LDS dest linear by lane within the wave.
__device__ __forceinline__ void gload16(const void* g, void* l) {
  __builtin_amdgcn_global_load_lds((const __attribute__((address_space(1))) void*)g,
                                   (__attribute__((address_space(3))) void*)l, 16, 0, 0);
}

// ---------------- convert x (f32 -> bf16), 8 elems/thread ----------------
__global__ __launch_bounds__(256) void convert_x_kernel(const float* __restrict__ x,
                                                        u16* __restrict__ xb) {
  int i = (blockIdx.x * 256 + threadIdx.x) * 8;
  float4 v0 = *(const float4*)(x + i);
  float4 v1 = *(const float4*)(x + i + 4);
  uint4 o;
  o.x = (uint32_t)f2bf(v0.x) | ((uint32_t)f2bf(v0.y) << 16);
  o.y = (uint32_t)f2bf(v0.z) | ((uint32_t)f2bf(v0.w) << 16);
  o.z = (uint32_t)f2bf(v1.x) | ((uint32_t)f2bf(v1.y) << 16);
  o.w = (uint32_t)f2bf(v1.z) | ((uint32_t)f2bf(v1.w) << 16);
  *(uint4*)(xb + i) = o;
}

// ---------- tiled transpose + convert: src f32 [z][R][C] -> dst bf16 [z][C][R] ----------
__global__ __launch_bounds__(256) void transpose_kernel(const float* __restrict__ src,
                                                        u16* __restrict__ dst, int R, int C) {
  __shared__ float tile[32][33];
  const int z = blockIdx.z;
  const float* s = src + (size_t)z * R * C;
  u16* d = dst + (size_t)z * R * C;
  const int tx = threadIdx.x, ty = threadIdx.y;  // 32 x 8
  const int r0 = blockIdx.y * 32, c0 = blockIdx.x * 32;
#pragma unroll
  for (int i = 0; i < 4; ++i)
    tile[ty + i * 8][tx] = s[(size_t)(r0 + ty + i * 8) * C + (c0 + tx)];
  __syncthreads();
#pragma unroll
  for (int i = 0; i < 4; ++i)
    d[(size_t)(c0 + ty + i * 8) * R + (r0 + tx)] = f2bf(tile[tx][ty + i * 8]);
}

// ---------------- RoPE tables: [1024 positions][64] cos/sin ----------------
__global__ __launch_bounds__(256) void rope_table_kernel(float* __restrict__ costab,
                                                         float* __restrict__ sintab) {
  int idx = blockIdx.x * 256 + threadIdx.x;  // 65536
  int p = idx >> 6, i = idx & 63;
  float ts = powf(10000.0f, (float)i * (1.0f / 64.0f));
  float ang = (float)p / ts;
  costab[idx] = cosf(ang);
  sintab[idx] = sinf(ang);
}

// ---------------- fused q/k/v projection GEMM (raw epilogue, v -> vT) ----------------
// 1D grid 576 = 32 m-tiles x 18 outputs, XCD-swizzled so each XCD owns contiguous
// newbids sharing one 512KB B-panel (L2 locality). 4 waves, wave tile 64x64.
// BK=64, single-buffer (R2 structure: the measured-best regime for this shape).
__global__ __launch_bounds__(256) void proj_gemm_kernel(
    const u16* __restrict__ xb, const u16* __restrict__ wqT, const u16* __restrict__ wkvT,
    u16* __restrict__ qraw, u16* __restrict__ kraw, u16* __restrict__ vT) {
  __shared__ alignas(16) u16 a_lds[128 * 64];
  __shared__ alignas(16) u16 b_lds[128 * 64];
  const int bid = blockIdx.x;
  const int newbid = (bid & 7) * 72 + (bid >> 3);  // 576 = 72*8, bijective
  const int y = newbid >> 5;        // 0..17
  const int m0 = (newbid & 31) * 128;
  const u16* Bt = (y < N_) ? (wqT + (size_t)y * H_ * D_) : (wkvT + (size_t)(y - N_) * H_ * D_);
  const int tid = threadIdx.x;
  const int w = tid >> 6, lane = tid & 63;
  const int g = lane >> 4, li = lane & 15;
  const int mrow = (w >> 1) * 64, wc = (w & 1) * 64;
  f32x4 acc[4][4];
#pragma unroll
  for (int i = 0; i < 4; ++i)
#pragma unroll
    for (int j = 0; j < 4; ++j) acc[i][j] = (f32x4){0.f, 0.f, 0.f, 0.f};

  for (int k0 = 0; k0 < D_; k0 += 64) {
    __syncthreads();
#pragma unroll
    for (int it = 0; it < 4; ++it) {
      int chunk = it * 256 + tid;            // 0..1023 16B-units
      int row = chunk >> 3, cu = chunk & 7;  // 128 rows x 8 x 16B
      gload16(xb + (size_t)(m0 + row) * D_ + k0 + ((cu ^ (row & 7)) << 3), &a_lds[chunk * 8]);
    }
#pragma unroll
    for (int it = 0; it < 4; ++it) {
      int chunk = it * 256 + tid;
      int row = chunk >> 3, cu = chunk & 7;
      gload16(Bt + (size_t)row * D_ + k0 + ((cu ^ (row & 7)) << 3), &b_lds[chunk * 8]);
    }
    __syncthreads();
#pragma unroll
    for (int c2 = 0; c2 < 2; ++c2) {
      bf16x8 af[4], bfr[4];
#pragma unroll
      for (int i = 0; i < 4; ++i) {
        int row = mrow + i * 16 + li;
        af[i] = *(const bf16x8*)((const char*)a_lds +
                                 row * 128 + ((c2 * 64 + g * 16) ^ ((row & 7) << 4)));
      }
#pragma unroll
      for (int j = 0; j < 4; ++j) {
        int row = wc + j * 16 + li;
        bfr[j] = *(const bf16x8*)((const char*)b_lds +
                                  row * 128 + ((c2 * 64 + g * 16) ^ ((row & 7) << 4)));
      }
#pragma unroll
      for (int i = 0; i < 4; ++i)
#pragma unroll
        for (int j = 0; j < 4; ++j)
          acc[i][j] = __builtin_amdgcn_mfma_f32_16x16x32_bf16(af[i], bfr[j], acc[i][j], 0, 0, 0);
    }
  }

  const int b = m0 >> 10;
  if (y == N_ + 1) {  // v -> vT[b][h][t], packed along t
    const int tbase0 = (m0 & 1023) + mrow;
#pragma unroll
    for (int i = 0; i < 4; ++i) {
      int tbase = tbase0 + i * 16 + g * 4;
#pragma unroll
      for (int j = 0; j < 4; ++j) {
        int h = wc + j * 16 + li;
        ushort4 pk;
        pk.x = f2bf(acc[i][j][0]);
        pk.y = f2bf(acc[i][j][1]);
        pk.z = f2bf(acc[i][j][2]);
        pk.w = f2bf(acc[i][j][3]);
        *(ushort4*)(vT + ((size_t)(b * H_ + h)) * T_ + tbase) = pk;
      }
    }
  } else {  // raw q (rows (b*N+y)*T + t) or raw k (rows bt); RoPE applied in next pass
    size_t rowbase = (y < N_) ? ((size_t)(b * N_ + y) * T_ + (m0 & 1023)) : (size_t)m0;
    u16* dst0 = (y < N_) ? qraw : kraw;
#pragma unroll
    for (int i = 0; i < 4; ++i)
#pragma unroll
      for (int r = 0; r < 4; ++r) {
        int trow = mrow + i * 16 + g * 4 + r;
        u16* dst = dst0 + (rowbase + trow) * H_;
#pragma unroll
        for (int j = 0; j < 4; ++j) dst[wc + j * 16 + li] = f2bf(acc[i][j][r]);
      }
  }
}

// ---------------- RoPE apply: qb = rope(qraw)*scale, kb = rope(kraw) ----------------
// 32 lanes per 128-elem row, 8 rows per block. Memory-bound (~40 MB traffic).
__global__ __launch_bounds__(256) void rope_apply_kernel(
    const u16* __restrict__ qraw, const u16* __restrict__ kraw,
    const int* __restrict__ segment_pos, const float* __restrict__ costab,
    const float* __restrict__ sintab, u16* __restrict__ qb, u16* __restrict__ kb) {
  const int rid = blockIdx.x * 8 + (threadIdx.x >> 5);
  const int j = threadIdx.x & 31;
  const u16* src;
  u16* dst;
  int bt;
  float scale;
  if (rid < BT_ * N_) {  // q rows: (b*N+n)*T + t
    src = qraw + (size_t)rid * H_;
    dst = qb + (size_t)rid * H_;
    int t = rid & (T_ - 1);
    int b = rid >> 14;  // T*N = 16384
    bt = b * T_ + t;
    scale = 0.08838834764831845f;  // 128^-0.5
  } else {  // k rows: bt
    int r2 = rid - BT_ * N_;
    src = kraw + (size_t)r2 * H_;
    dst = kb + (size_t)r2 * H_;
    bt = r2;
    scale = 1.0f;
  }
  int p = segment_pos[bt];
  p = p < 0 ? 0 : (p > 1023 ? 1023 : p);
  uint32_t ua = *(const uint32_t*)(src + 2 * j);       // h = 2j, 2j+1
  uint32_t ub = *(const uint32_t*)(src + 64 + 2 * j);  // h + 64
  float2 cv = *(const float2*)(costab + p * 64 + 2 * j);
  float2 sv = *(const float2*)(sintab + p * 64 + 2 * j);
  float f1a = bf2f(ua & 0xffffu), f1b = bf2f(ua >> 16);
  float f2a = bf2f(ub & 0xffffu), f2b = bf2f(ub >> 16);
  float o1a = (f1a * cv.x - f2a * sv.x) * scale;
  float o1b = (f1b * cv.y - f2b * sv.y) * scale;
  float o2a = (f2a * cv.x + f1a * sv.x) * scale;
  float o2b = (f2b * cv.y + f1b * sv.y) * scale;
  *(uint32_t*)(dst + 2 * j) = (uint32_t)f2bf(o1a) | ((uint32_t)f2bf(o1b) << 16);
  *(uint32_t*)(dst + 64 + 2 * j) = (uint32_t)f2bf(o2a) | ((uint32_t)f2bf(o2b) << 16);
}

// ---------------- flash attention (swapped-QK, swizzled LDS, 2-phase dbuf) ---------
// grid: (T/64, B*N). qt = 15 - bx (heavy blocks first). 4 waves; wave w owns q rows
// [qt*64+16w, +16). K [64][128] swz, V^T [128][64] swz, P^T per-wave [16][64] swz.
__global__ __launch_bounds__(256) void attn_kernel(const u16* __restrict__ qb,
                                                   const u16* __restrict__ kb,
                                                   const u16* __restrict__ vT,
                                                   u16* __restrict__ enc) {
  __shared__ alignas(16) u16 k_lds[2][64 * 128];
  __shared__ alignas(16) u16 v_lds[2][128 * 64];
  __shared__ alignas(16) u16 p_lds[4 * 16 * 64];
  const int qt = (int)(gridDim.x - 1 - blockIdx.x);
  const int bn = blockIdx.y;
  const int b = bn >> 4, n = bn & 15;
  const int tid = threadIdx.x, w = tid >> 6, lane = tid & 63;
  const int g = lane >> 4, li = lane & 15;
  const int t0 = qt * 64 + w * 16;
  char* pbase = (char*)p_lds + w * 2048;

  bf16x8 qf[4];  // Q as B-fragment: lane -> Q[t0+li][c*32+g*8+e]
  {
    const u16* qrow = qb + ((size_t)(b * N_ + n) * T_ + (t0 + li)) * H_;
#pragma unroll
    for (int c = 0; c < 4; ++c) qf[c] = *(const bf16x8*)(qrow + c * 32 + g * 8);
  }
  f32x4 o[8];
#pragma unroll
  for (int j = 0; j < 8; ++j) o[j] = (f32x4){0.f, 0.f, 0.f, 0.f};
  float m = -3e38f, lsum = 0.f;

  auto stageKV = [&](int buf, int s0) {
#pragma unroll
    for (int it = 0; it < 4; ++it) {
      int chunk = it * 256 + tid;
      int row = chunk >> 4, cu = chunk & 15;
      gload16(kb + ((size_t)b * T_ + s0 + row) * H_ + ((cu ^ (row & 7)) << 3),
              &k_lds[buf][chunk * 8]);
    }
#pragma unroll
    for (int it = 0; it < 4; ++it) {
      int chunk = it * 256 + tid;
      int row = chunk >> 3, cu = chunk & 7;
      gload16(vT + ((size_t)(b * H_ + row)) * T_ + s0 + ((cu ^ (row & 7)) << 3),
              &v_lds[buf][chunk * 8]);
    }
  };

  stageKV(0, 0);
  __syncthreads();
  int cur = 0;
  for (int st = 0; st <= qt; ++st) {
    if (st < qt) stageKV(cur ^ 1, (st + 1) * 64);  // prefetch next K/V tile

    // S^T = K x Q : sacc[fn] lane -> S[t=t0+li][s = s0+fn*16+g*4+r]
    f32x4 sacc[4];
#pragma unroll
    for (int fn = 0; fn < 4; ++fn) sacc[fn] = (f32x4){0.f, 0.f, 0.f, 0.f};
#pragma unroll
    for (int c = 0; c < 4; ++c)
#pragma unroll
      for (int fn = 0; fn < 4; ++fn) {
        int row = fn * 16 + li;
        bf16x8 kf = *(const bf16x8*)((const char*)&k_lds[cur][0] +
                                     row * 256 + ((c * 64 + g * 16) ^ ((row & 7) << 4)));
        sacc[fn] = __builtin_amdgcn_mfma_f32_16x16x32_bf16(kf, qf[c], sacc[fn], 0, 0, 0);
      }

    if (st == qt) {  // diagonal: mask s_local > t_local
#pragma unroll
      for (int fn = 0; fn < 4; ++fn)
#pragma unroll
        for (int r = 0; r < 4; ++r)
          if (fn * 16 + g * 4 + r > w * 16 + li) sacc[fn][r] = KMASK;
    }

    // online softmax: row t = t0+li spread over lanes {li, li+16, li+32, li+48}
    float mx = -3e38f;
#pragma unroll
    for (int fn = 0; fn < 4; ++fn)
#pragma unroll
      for (int r = 0; r < 4; ++r) mx = fmaxf(mx, sacc[fn][r]);
    mx = fmaxf(mx, __shfl_xor(mx, 16, 64));
    mx = fmaxf(mx, __shfl_xor(mx, 32, 64));
    float mn = fmaxf(m, mx);
    float alpha = __expf(m - mn);
    m = mn;
    float ps = 0.f;
#pragma unroll
    for (int fn = 0; fn < 4; ++fn)
#pragma unroll
      for (int r = 0; r < 4; ++r) {
        float p = __expf(sacc[fn][r] - mn);
        sacc[fn][r] = p;
        ps += p;
      }
    ps += __shfl_xor(ps, 16, 64);
    ps += __shfl_xor(ps, 32, 64);
    lsum = lsum * alpha + ps;

    // write P^T rows t=li: 4 x ds_write_b64, s-contiguous (per-wave region, no barrier)
#pragma unroll
    for (int fn = 0; fn < 4; ++fn) {
      ushort4 pk;
      pk.x = f2bf(sacc[fn][0]);
      pk.y = f2bf(sacc[fn][1]);
      pk.z = f2bf(sacc[fn][2]);
      pk.w = f2bf(sacc[fn][3]);
      *(ushort4*)(pbase + li * 128 + ((fn * 32 + g * 8) ^ ((li & 7) << 4))) = pk;
    }

    // rescale O (rows g*4+r) by alpha of that row
#pragma unroll
    for (int r = 0; r < 4; ++r) {
      float ar = __shfl(alpha, g * 4 + r, 64);
#pragma unroll
      for (int hn = 0; hn < 8; ++hn) o[hn][r] *= ar;
    }

    // PV: o[hn] += P(A) x V(B)
#pragma unroll
    for (int c2 = 0; c2 < 2; ++c2) {
      bf16x8 pf = *(const bf16x8*)(pbase + li * 128 + ((c2 * 64 + g * 16) ^ ((li & 7) << 4)));
#pragma unroll
      for (int hn = 0; hn < 8; ++hn) {
        int hrow = hn * 16 + li;
        bf16x8 vf = *(const bf16x8*)((const char*)&v_lds[cur][0] +
                                     hrow * 128 + ((c2 * 64 + g * 16) ^ ((li & 7) << 4)));
        o[hn] = __builtin_amdgcn_mfma_f32_16x16x32_bf16(pf, vf, o[hn], 0, 0, 0);
      }
    }
    __syncthreads();  // drains prefetch; all waves done with buf[cur]
    cur ^= 1;
  }

#pragma unroll
  for (int r = 0; r < 4; ++r) {
    float lr = __shfl(lsum, g * 4 + r, 64);
    float inv = 1.0f / lr;
    int t = qt * 64 + w * 16 + g * 4 + r;
    u16* dst = enc + ((size_t)(b * T_ + t)) * (N_ * H_) + n * H_;
#pragma unroll
    for (int hn = 0; hn < 8; ++hn) dst[hn * 16 + li] = f2bf(o[hn][r] * inv);
  }
}

// ---------------- output projection GEMM: out = enc @ wo_flat ----------------
// 1D grid 512 = 32 m-tiles x 16 n-tiles, XCD-swizzled (contiguous newbids share
// the woT n-panel). BK=64, single-buffer, 64x64 wave tiles.
__global__ __launch_bounds__(256) void out_gemm_kernel(const u16* __restrict__ enc,
                                                       const u16* __restrict__ woT,
                                                       float* __restrict__ out) {
  __shared__ alignas(16) u16 a_lds[128 * 64];
  __shared__ alignas(16) u16 b_lds[128 * 64];
  const int bid = blockIdx.x;
  const int newbid = (bid & 7) * 64 + (bid >> 3);  // 512 = 64*8, bijective
  const int m0 = (newbid & 31) * 128;
  const int n0 = (newbid >> 5) * 128;
  const int tid = threadIdx.x, w = tid >> 6, lane = tid & 63;
  const int g = lane >> 4, li = lane & 15;
  const int mrow = (w >> 1) * 64, wc = (w & 1) * 64;
  f32x4 acc[4][4];
#pragma unroll
  for (int i = 0; i < 4; ++i)
#pragma unroll
    for (int j = 0; j < 4; ++j) acc[i][j] = (f32x4){0.f, 0.f, 0.f, 0.f};

  for (int k0 = 0; k0 < D_; k0 += 64) {
    __syncthreads();
#pragma unroll
    for (int it = 0; it < 4; ++it) {
      int chunk = it * 256 + tid;
      int row = chunk >> 3, cu = chunk & 7;
      gload16(enc + (size_t)(m0 + row) * D_ + k0 + ((cu ^ (row & 7)) << 3), &a_lds[chunk * 8]);
    }
#pragma unroll
    for (int it = 0; it < 4; ++it) {
      int chunk = it * 256 + tid;
      int row = chunk >> 3, cu = chunk & 7;
      gload16(woT + (size_t)(n0 + row) * D_ + k0 + ((cu ^ (row & 7)) << 3), &b_lds[chunk * 8]);
    }
    __syncthreads();
#pragma unroll
    for (int c2 = 0; c2 < 2; ++c2) {
      bf16x8 af[4], bfr[4];
#pragma unroll
      for (int i = 0; i < 4; ++i) {
        int row = mrow + i * 16 + li;
        af[i] = *(const bf16x8*)((const char*)a_lds +
                                 row * 128 + ((c2 * 64 + g * 16) ^ ((row & 7) << 4)));
      }
#pragma unroll
      for (int j = 0; j < 4; ++j) {
        int row = wc + j * 16 + li;
        bfr[j] = *(const bf16x8*)((const char*)b_lds +
                                  row * 128 + ((c2 * 64 + g * 16) ^ ((row & 7) << 4)));
      }
#pragma unroll
      for (int i = 0; i < 4; ++i)
#pragma unroll
        for (int j = 0; j < 4; ++j)
          acc[i][j] = __builtin_amdgcn_mfma_f32_16x16x32_bf16(af[i], bfr[j], acc[i][j], 0, 0, 0);
    }
  }
#pragma unroll
  for (int i = 0; i < 4; ++i)
#pragma unroll
    for (int r = 0; r < 4; ++r) {
      int bt = m0 + mrow + i * 16 + g * 4 + r;
      float* dst = out + (size_t)bt * D_ + n0 + wc;
#pragma unroll
      for (int j = 0; j < 4; ++j) dst[j * 16 + li] = acc[i][j][r];
    }
}

// ---------------- launch ----------------
extern "C" void kernel_launch(void* const* d_in, const int* in_sizes, int n_in,
                              void* d_out, int out_size, void* d_ws, size_t ws_size,
                              hipStream_t stream) {
  const float* x = (const float*)d_in[0];
  const float* wq = (const float*)d_in[1];
  const float* wkv = (const float*)d_in[2];
  const float* wo = (const float*)d_in[3];
  const int* segment_pos = (const int*)d_in[4];
  // d_in[5] = attn_mask: causal tril for this problem; applied via index causality.
  float* out = (float*)d_out;

  char* ws = (char*)d_ws;
  size_t off = 0;
  auto alloc = [&](size_t bytes) -> void* {
    void* p = ws + off;
    off += (bytes + 255) & ~(size_t)255;
    return p;
  };
  u16* xb   = (u16*)alloc((size_t)BT_ * D_ * 2);
  u16* wqT  = (u16*)alloc((size_t)N_ * H_ * D_ * 2);
  u16* wkvT = (u16*)alloc((size_t)2 * H_ * D_ * 2);
  u16* woT  = (u16*)alloc((size_t)D_ * N_ * H_ * 2);
  u16* qb   = (u16*)alloc((size_t)B_ * N_ * T_ * H_ * 2);
  u16* kb   = (u16*)alloc((size_t)B_ * T_ * H_ * 2);
  u16* kraw = (u16*)alloc((size_t)B_ * T_ * H_ * 2);
  u16* vT   = (u16*)alloc((size_t)B_ * H_ * T_ * 2);
  u16* enc  = (u16*)alloc((size_t)BT_ * N_ * H_ * 2);
  float* costab = (float*)alloc(1024 * 64 * 4);
  float* sintab = (float*)alloc(1024 * 64 * 4);
  u16* qraw = enc;  // alias: qraw consumed by rope_apply before attn overwrites enc

  convert_x_kernel<<<BT_ * D_ / 8 / 256, 256, 0, stream>>>(x, xb);
  dim3 tb(32, 8);
  transpose_kernel<<<dim3(H_ / 32, D_ / 32, N_), tb, 0, stream>>>(wq, wqT, D_, H_);
  transpose_kernel<<<dim3(H_ / 32, D_ / 32, 2), tb, 0, stream>>>(wkv, wkvT, D_, H_);
  transpose_kernel<<<dim3(D_ / 32, D_ / 32, 1), tb, 0, stream>>>(wo, woT, N_ * H_, D_);
  rope_table_kernel<<<256, 256, 0, stream>>>(costab, sintab);
  proj_gemm_kernel<<<576, 256, 0, stream>>>(xb, wqT, wkvT, qraw, kraw, vT);
  rope_apply_kernel<<<(BT_ * N_ + BT_) / 8, 256, 0, stream>>>(qraw, kraw, segment_pos,
                                                              costab, sintab, qb, kb);
  attn_kernel<<<dim3(T_ / 64, B_ * N_), 256, 0, stream>>>(qb, kb, vT, enc);
  out_gemm_kernel<<<512, 256, 0, stream>>>(enc, woT, out);
}